// Round 10
// baseline (140.358 us; speedup 1.0000x reference)
//
#include <hip/hip_runtime.h>
#include <hip/hip_fp16.h>

typedef __attribute__((ext_vector_type(8))) _Float16 half8;
typedef __attribute__((ext_vector_type(2))) __fp16 fp16x2;
typedef __attribute__((ext_vector_type(4))) float f32x4;
typedef unsigned short u16;
typedef unsigned int u32;

__device__ __forceinline__ u16 f2h(float f) {
  union { _Float16 h; u16 u; } cv; cv.h = (_Float16)f; return cv.u;
}

__device__ __forceinline__ u32 pkrtz(float a, float b) {
  union { fp16x2 h; u32 u; } cv;
  cv.h = __builtin_amdgcn_cvt_pkrtz(a, b);
  return cv.u;
}

__device__ __forceinline__ f32x4 mfma16h(half8 a, half8 b, f32x4 c) {
  return __builtin_amdgcn_mfma_f32_16x16x32_f16(a, b, c, 0, 0, 0);
}

__device__ __forceinline__ void gload_lds16(const void* g, void* l) {
  __builtin_amdgcn_global_load_lds(
      (const __attribute__((address_space(1))) void*)g,
      (__attribute__((address_space(3))) void*)l, 16, 0, 0);
}

__device__ __forceinline__ half8 ldh8(const char* p) {
  union { half8 h; int4 v; } r; r.v = *(const int4*)p; return r.h;
}

// 8-wide fp16 product via v_pk_mul_f16
__device__ __forceinline__ uint4 pkmul4(uint4 x, uint4 y) {
  union U { uint4 v; __half2 h[4]; };
  U X, Y, E; X.v = x; Y.v = y;
  #pragma unroll
  for (int i = 0; i < 4; i++) E.h[i] = __hmul2(X.h[i], Y.h[i]);
  return E.v;
}
__device__ __forceinline__ half8 as_h8(uint4 v) {
  union { uint4 v; half8 h; } r; r.v = v; return r.h;
}

// ---- one row of weight-norm (fp16 out), wave-cooperative ----
__device__ __forceinline__ void wn_row(const float* __restrict__ v,
                                       const float* __restrict__ g,
                                       int K, int Nreal, u16* __restrict__ outW,
                                       int row, int l) {
  if (row >= Nreal) {
    for (int k = l; k < K; k += 64) outW[row * K + k] = 0;
    return;
  }
  const float* vr = v + (size_t)row * K;
  float ss = 0.f;
  for (int k = l * 4; k < K; k += 256) {
    f32x4 x = *(const f32x4*)(vr + k);
    ss += x.x * x.x + x.y * x.y + x.z * x.z + x.w * x.w;
  }
  #pragma unroll
  for (int m = 32; m >= 1; m >>= 1) ss += __shfl_xor(ss, m, 64);
  const float scale = g[row] / sqrtf(ss);
  for (int k = l; k < K; k += 64) outW[row * K + k] = f2h(vr[k] * scale);
}

// ---- merged weight-norm prep: all 4 weight matrices in one launch ----
// blocks [0,128): Wobj; [128,256): Wq; [256,320): W1f [kc(16)][row(256)][32]
// (plain layout, read from global in edge kernel); [320,324): W2p.
__global__ __launch_bounds__(256) void wn_all(
    const float* __restrict__ v_obj, const float* __restrict__ g_obj,
    const float* __restrict__ v_q,   const float* __restrict__ g_q,
    const float* __restrict__ v_l1,  const float* __restrict__ g_l1,
    const float* __restrict__ v_l2,  const float* __restrict__ g_l2,
    u16* __restrict__ Wobjh, u16* __restrict__ Wqh,
    u16* __restrict__ W1f,   u16* __restrict__ W2p) {
  const int b = blockIdx.x;
  const int sub = threadIdx.x >> 6, l = threadIdx.x & 63;
  if (b < 128) {
    wn_row(v_obj, g_obj, 2048, 512, Wobjh, b * 4 + sub, l);
  } else if (b < 256) {
    wn_row(v_q, g_q, 1024, 512, Wqh, (b - 128) * 4 + sub, l);
  } else if (b < 320) {
    const int row = (b - 256) * 4 + sub;
    const float* vr = v_l1 + (size_t)row * 512;
    float ss = 0.f;
    for (int k = l * 4; k < 512; k += 256) {
      f32x4 x = *(const f32x4*)(vr + k);
      ss += x.x * x.x + x.y * x.y + x.z * x.z + x.w * x.w;
    }
    #pragma unroll
    for (int m = 32; m >= 1; m >>= 1) ss += __shfl_xor(ss, m, 64);
    const float scale = g_l1[row] / sqrtf(ss);
    for (int c = l; c < 512; c += 64)
      W1f[(c >> 5) * 8192 + row * 32 + (c & 31)] = f2h(vr[c] * scale);
  } else {
    wn_row(v_l2, g_l2, 256, 8, W2p, (b - 320) * 4 + sub, l);
  }
}

// ---- bulk fp32 -> fp16 convert ----
__global__ void cvt_f16(const float* __restrict__ in, u16* __restrict__ out, int n) {
  const int i = (blockIdx.x * 256 + threadIdx.x) * 8;
  if (i >= n) return;
  f32x4 a = *(const f32x4*)(in + i);
  f32x4 b = *(const f32x4*)(in + i + 4);
  uint4 r;
  r.x = pkrtz(a.x, a.y); r.y = pkrtz(a.z, a.w);
  r.z = pkrtz(b.x, b.y); r.w = pkrtz(b.z, b.w);
  *(uint4*)(out + i) = r;
}

// ---- pos map (stride 1408 per batch) ----
__global__ void pos_init(int* __restrict__ pos, int n) {
  int t = blockIdx.x * 256 + threadIdx.x;
  if (t < n) pos[t] = -1;
}
__global__ void pos_scatter(const int* __restrict__ indexes, int* __restrict__ pos, int n) {
  int m = blockIdx.x * 256 + threadIdx.x;
  if (m >= n) return;
  int idx = indexes[m];
  int bi = idx / 1296;
  int rem = idx - bi * 1296;
  pos[bi * 1408 + rem] = m;
}

// ================= LDS-staged stage-1 GEMM, fp16, 128x64 tile (unchanged) =================
template <int MODE>
__global__ __launch_bounds__(256, 3) void gemm_lds(
    const u16* __restrict__ Ab, const u16* __restrict__ Wb,
    int K, int nstep, const float* __restrict__ bias,
    float* __restrict__ fout, u16* __restrict__ o_a2) {
  __shared__ char smem[2][24576];
  const int t = threadIdx.x, l = t & 63, w = t >> 6;
  const int lr = l & 15, lg = l >> 4;
  const int wm = w & 1, wn2 = w >> 1;
  const int bm = blockIdx.x * 128, bn = blockIdx.y * 64;
  const int kbase = (MODE == 0) ? blockIdx.z * 128 : 0;
  const int ldb = K * 2;

  const char* Abase = (const char*)(Ab + (size_t)bm * K + kbase);
  const char* Bbase = (const char*)(Wb + (size_t)bn * K + kbase);

  auto stage = [&](int buf, int ks) {
    const char* asrc = Abase + ks * 128;
    const char* bsrc = Bbase + ks * 128;
    #pragma unroll
    for (int it = 0; it < 4; it++) {
      const int c = it * 256 + w * 64 + l;
      const int row = c >> 3;
      const int cb = ((c & 7) * 16) ^ ((row & 7) << 4);
      gload_lds16(asrc + (size_t)row * ldb + cb, &smem[buf][(it * 256 + w * 64) * 16]);
    }
    #pragma unroll
    for (int it = 0; it < 2; it++) {
      const int c = it * 256 + w * 64 + l;
      const int row = c >> 3;
      const int cb = ((c & 7) * 16) ^ ((row & 7) << 4);
      gload_lds16(bsrc + (size_t)row * ldb + cb,
                  &smem[buf][16384 + (it * 256 + w * 64) * 16]);
    }
  };

  stage(0, 0);
  asm volatile("s_waitcnt vmcnt(0)" ::: "memory");
  __builtin_amdgcn_s_barrier();

  f32x4 acc[4][2] = {};
  for (int ks = 0; ks < nstep; ks++) {
    const int cur = ks & 1;
    if (ks + 1 < nstep) stage(cur ^ 1, ks + 1);
    const char* As = smem[cur];
    const char* Bs = smem[cur] + 16384;
    #pragma unroll
    for (int kk = 0; kk < 2; kk++) {
      half8 af[4], bf[2];
      #pragma unroll
      for (int m = 0; m < 4; m++) {
        const int r = wm * 64 + m * 16 + lr;
        af[m] = ldh8(As + r * 128 + ((kk * 64 + lg * 16) ^ ((lr & 7) << 4)));
      }
      #pragma unroll
      for (int n = 0; n < 2; n++) {
        const int r = wn2 * 32 + n * 16 + lr;
        bf[n] = ldh8(Bs + r * 128 + ((kk * 64 + lg * 16) ^ ((lr & 7) << 4)));
      }
      #pragma unroll
      for (int m = 0; m < 4; m++)
        #pragma unroll
        for (int n = 0; n < 2; n++)
          acc[m][n] = mfma16h(af[m], bf[n], acc[m][n]);
    }
    asm volatile("s_waitcnt vmcnt(0)" ::: "memory");
    __builtin_amdgcn_s_barrier();
  }

  #pragma unroll
  for (int n = 0; n < 2; n++) {
    const int c = bn + wn2 * 32 + n * 16 + lr;
    const float bv = (MODE == 1) ? bias[c] : 0.f;
    #pragma unroll
    for (int m = 0; m < 4; m++) {
      #pragma unroll
      for (int q = 0; q < 4; q++) {
        const int r = bm + wm * 64 + m * 16 + lg * 4 + q;
        const float val = acc[m][n][q];
        if (MODE == 0) {
          fout[((size_t)blockIdx.z * 128 + r) * 512 + c] = val;
        } else {
          o_a2[(size_t)r * 512 + c] = f2h(val + bv);
        }
      }
    }
  }
}

// ---- split-K reduce for qp -> fp16 ----
__global__ void qp_reduce(const float* __restrict__ part, const float* __restrict__ bq,
                          u16* __restrict__ qp_h) {
  const int i = (blockIdx.x * 256 + threadIdx.x) * 4;
  f32x4 s = *(const f32x4*)(part + i);
  #pragma unroll
  for (int k = 1; k < 8; k++) {
    f32x4 v = *(const f32x4*)(part + (size_t)k * 65536 + i);
    s.x += v.x; s.y += v.y; s.z += v.z; s.w += v.w;
  }
  const int c = i & 511;
  uint2 r;
  r.x = pkrtz(s.x + bq[c], s.y + bq[c + 1]);
  r.y = pkrtz(s.z + bq[c + 2], s.w + bq[c + 3]);
  *(uint2*)(qp_h + i) = r;
}

// ================= fused edge kernel v9: barrier-free K-loop =================
// nf/qp tables are static in LDS (written once in prologue). W1 B-fragments
// read DIRECTLY from global (L1/L2-hot; 16 contiguous rows x 64B = coalesced
// 1KB wave load). ZERO barriers in the 16-iteration K-loop -> waves fully
// decoupled, compiler pipelines bf prefetch across kc.
// LDS: nf[36][1040] | qp 1KB = 38,464 B. Epilogue h-tile [64][528] aliases nf
// (two phases of 64 rows).
#define OFF_QP 37440
#define EDGE_SMEM 38464

__global__ __launch_bounds__(512, 4) void edge_v9(
    const u16* __restrict__ NFg, const u16* __restrict__ QPg,
    const u16* __restrict__ W1f, const float* __restrict__ b1,
    const u16* __restrict__ W2p, const float* __restrict__ b2,
    const int* __restrict__ pos, float* __restrict__ out) {
  extern __shared__ char smem[];
  const int t = threadIdx.x, l = t & 63, w = t >> 6;
  const int lr = l & 15, lg = l >> 4;
  const int wm = w & 1, wn = w >> 1;
  const int bi = blockIdx.y;
  const int mb = blockIdx.x * 128;

  // ---- prologue: stage nf rows 0..35 + qp row into LDS ----
  #pragma unroll
  for (int it = 0; it < 5; it++) {
    const int row = it * 8 + w;            // wave-uniform
    if (row < 36) {
      gload_lds16(NFg + (size_t)(bi * 36 + row) * 512 + l * 8, smem + row * 1040);
    } else if (row == 36) {
      gload_lds16(QPg + (size_t)bi * 512 + l * 8, smem + OFF_QP);
    }
  }

  // ---- per-thread A-gen offsets for the 4 m-tiles ----
  int xoff[4], yoff[4];
  #pragma unroll
  for (int m = 0; m < 4; m++) {
    const int gr = mb + wm * 64 + m * 16 + lr;
    const int iiu = gr / 36;
    const int jj = gr - iiu * 36;
    const int ii = (iiu > 35) ? 35 : iiu;
    xoff[m] = ii * 1040 + lg * 16;
    yoff[m] = jj * 1040 + lg * 16;
  }
  const int qoff = OFF_QP + lg * 16;

  // per-lane W1 global base: row = wn*64 + lr, elems lg*8..; +n*512, +kc*8192
  const u16* wbase = W1f + (size_t)(wn * 64 + lr) * 32 + lg * 8;

  float b1v[4];
  #pragma unroll
  for (int n = 0; n < 4; n++) b1v[n] = b1[wn * 64 + n * 16 + lr];

  asm volatile("s_waitcnt vmcnt(0)" ::: "memory");
  __builtin_amdgcn_s_barrier();           // tables ready

  // ---- barrier-free K-loop ----
  f32x4 acc[4][4] = {};
  for (int kc = 0; kc < 16; kc++) {
    const int kb = kc * 64;
    half8 bf[4];
    #pragma unroll
    for (int n = 0; n < 4; n++)
      bf[n] = ldh8((const char*)(wbase + kc * 8192 + n * 512));
    const uint4 qv = *(const uint4*)(smem + qoff + kb);
    #pragma unroll
    for (int m = 0; m < 4; m++) {
      uint4 x = *(const uint4*)(smem + xoff[m] + kb);
      uint4 y = *(const uint4*)(smem + yoff[m] + kb);
      half8 af = as_h8(pkmul4(pkmul4(x, y), qv));
      #pragma unroll
      for (int n = 0; n < 4; n++)
        acc[m][n] = mfma16h(af, bf[n], acc[m][n]);
    }
  }

  // ---- epilogue: two phases of 64 rows; h-tile [64][528B] aliases nf ----
  half8 w2f[8];
  #pragma unroll
  for (int kk = 0; kk < 8; kk++)
    w2f[kk] = ldh8((const char*)(W2p + lr * 256 + kk * 32 + lg * 8));

  #pragma unroll
  for (int ph = 0; ph < 2; ph++) {
    __syncthreads();                       // nf/h free to overwrite
    if (wm == ph) {
      #pragma unroll
      for (int m = 0; m < 4; m++) {
        #pragma unroll
        for (int n = 0; n < 4; n++) {
          const int c = wn * 64 + n * 16 + lr;
          #pragma unroll
          for (int qq = 0; qq < 2; qq++) {
            const float v0 = fmaxf(acc[m][n][2 * qq] + b1v[n], 0.f);
            const float v1 = fmaxf(acc[m][n][2 * qq + 1] + b1v[n], 0.f);
            const u32 p = pkrtz(v0, v1);
            const int r = m * 16 + lg * 4 + 2 * qq;
            *(u16*)(smem + r * 528 + c * 2) = (u16)p;
            *(u16*)(smem + (r + 1) * 528 + c * 2) = (u16)(p >> 16);
          }
        }
      }
    }
    __syncthreads();                       // h ready
    if (w < 4) {                           // GEMM2: 4 tiles of 16 rows
      f32x4 a2c = {0.f, 0.f, 0.f, 0.f};
      #pragma unroll
      for (int kk = 0; kk < 8; kk++) {
        half8 af = ldh8(smem + (w * 16 + lr) * 528 + kk * 64 + lg * 16);
        a2c = mfma16h(af, w2f[kk], a2c);
      }
      if (lr < 8) {
        const float b2v = b2[lr];
        #pragma unroll
        for (int q = 0; q < 4; q++) {
          const int rl = ph * 64 + w * 16 + lg * 4 + q;
          const int m = pos[bi * 1408 + mb + rl];
          if (m >= 0) out[(size_t)m * 8 + lr] = a2c[q] + b2v;
        }
      }
    }
  }
}

extern "C" void kernel_launch(void* const* d_in, const int* in_sizes, int n_in,
                              void* d_out, int out_size, void* d_ws, size_t ws_size,
                              hipStream_t stream) {
  const float* node_feats = (const float*)d_in[0];
  const float* q_feats    = (const float*)d_in[1];
  const int*   indexes    = (const int*)d_in[2];
  const float* v_obj = (const float*)d_in[3];
  const float* g_obj = (const float*)d_in[4];
  const float* b_obj = (const float*)d_in[5];
  const float* v_q   = (const float*)d_in[6];
  const float* g_q   = (const float*)d_in[7];
  const float* b_q   = (const float*)d_in[8];
  const float* v_l1  = (const float*)d_in[9];
  const float* g_l1  = (const float*)d_in[10];
  const float* b_l1  = (const float*)d_in[11];
  const float* v_l2  = (const float*)d_in[12];
  const float* g_l2  = (const float*)d_in[13];
  const float* b_l2  = (const float*)d_in[14];
  float* out = (float*)d_out;

  char* ws = (char*)d_ws;
  u16*   node_h = (u16*)(ws + 0);               // 18,874,368
  u16*   q_h    = (u16*)(ws + 18874368);        //    262,144
  u16*   Wobjh  = (u16*)(ws + 19136512);        //  2,097,152
  u16*   Wqh    = (u16*)(ws + 21233664);        //  1,048,576
  u16*   W1f    = (u16*)(ws + 22282240);        //    262,144 (16x256x32 fp16)
  u16*   W2p    = (u16*)(ws + 22544384);        //      8,192
  u16*   qp_h   = (u16*)(ws + 22552576);        //    131,072 (128x512 fp16)
  u16*   A2h    = (u16*)(ws + 22683648);        //  4,718,592 (nf fp16)
  int*   pos    = (int*)(ws + 27402240);        //    720,896 (128x1408)
  float* part   = (float*)(ws + 28123136);      //  2,097,152

  wn_all<<<dim3(324), dim3(256), 0, stream>>>(v_obj, g_obj, v_q, g_q, v_l1, g_l1,
                                              v_l2, g_l2, Wobjh, Wqh, W1f, W2p);

  cvt_f16<<<dim3(4608), dim3(256), 0, stream>>>(node_feats, node_h, 9437184);
  cvt_f16<<<dim3(64),   dim3(256), 0, stream>>>(q_feats,    q_h,    131072);

  pos_init<<<dim3(704), dim3(256), 0, stream>>>(pos, 128 * 1408);
  pos_scatter<<<dim3(630), dim3(256), 0, stream>>>(indexes, pos, 161280);

  gemm_lds<0><<<dim3(1, 8, 8), dim3(256), 0, stream>>>(q_h, Wqh, 1024, 2, nullptr,
                                                       part, nullptr);
  qp_reduce<<<dim3(64), dim3(256), 0, stream>>>(part, b_q, qp_h);

  gemm_lds<1><<<dim3(36, 8), dim3(256), 0, stream>>>(node_h, Wobjh, 2048, 32, b_obj,
                                                     nullptr, A2h);

  edge_v9<<<dim3(11, 128), dim3(512), EDGE_SMEM, stream>>>(A2h, qp_h, W1f, b_l1,
                                                           W2p, b_l2, pos, out);
}

// Round 11
// 119.864 us; speedup vs baseline: 1.1710x; 1.1710x over previous
//
#include <hip/hip_runtime.h>
#include <hip/hip_fp16.h>

typedef __attribute__((ext_vector_type(8))) _Float16 half8;
typedef __attribute__((ext_vector_type(2))) __fp16 fp16x2;
typedef __attribute__((ext_vector_type(4))) float f32x4;
typedef unsigned short u16;
typedef unsigned int u32;

__device__ __forceinline__ u16 f2h(float f) {
  union { _Float16 h; u16 u; } cv; cv.h = (_Float16)f; return cv.u;
}

__device__ __forceinline__ u32 pkrtz(float a, float b) {
  union { fp16x2 h; u32 u; } cv;
  cv.h = __builtin_amdgcn_cvt_pkrtz(a, b);
  return cv.u;
}

__device__ __forceinline__ f32x4 mfma16h(half8 a, half8 b, f32x4 c) {
  return __builtin_amdgcn_mfma_f32_16x16x32_f16(a, b, c, 0, 0, 0);
}

__device__ __forceinline__ void gload_lds16(const void* g, void* l) {
  __builtin_amdgcn_global_load_lds(
      (const __attribute__((address_space(1))) void*)g,
      (__attribute__((address_space(3))) void*)l, 16, 0, 0);
}

__device__ __forceinline__ half8 ldh8(const char* p) {
  union { half8 h; int4 v; } r; r.v = *(const int4*)p; return r.h;
}

// 8-wide fp16 product via v_pk_mul_f16
__device__ __forceinline__ uint4 pkmul4(uint4 x, uint4 y) {
  union U { uint4 v; __half2 h[4]; };
  U X, Y, E; X.v = x; Y.v = y;
  #pragma unroll
  for (int i = 0; i < 4; i++) E.h[i] = __hmul2(X.h[i], Y.h[i]);
  return E.v;
}
__device__ __forceinline__ half8 as_h8(uint4 v) {
  union { uint4 v; half8 h; } r; r.v = v; return r.h;
}

// ---- one row of weight-norm (fp16 out), wave-cooperative ----
__device__ __forceinline__ void wn_row(const float* __restrict__ v,
                                       const float* __restrict__ g,
                                       int K, int Nreal, u16* __restrict__ outW,
                                       int row, int l) {
  if (row >= Nreal) {
    for (int k = l; k < K; k += 64) outW[row * K + k] = 0;
    return;
  }
  const float* vr = v + (size_t)row * K;
  float ss = 0.f;
  for (int k = l * 4; k < K; k += 256) {
    f32x4 x = *(const f32x4*)(vr + k);
    ss += x.x * x.x + x.y * x.y + x.z * x.z + x.w * x.w;
  }
  #pragma unroll
  for (int m = 32; m >= 1; m >>= 1) ss += __shfl_xor(ss, m, 64);
  const float scale = g[row] / sqrtf(ss);
  for (int k = l; k < K; k += 64) outW[row * K + k] = f2h(vr[k] * scale);
}

// ---- merged weight-norm prep ----
// blocks [0,128): Wobj; [128,256): Wq; [256,320): W1f [kc(16)][row(256)][32]
// with quad q stored at q ^ ((row>>1)&3); [320,324): W2p.
__global__ __launch_bounds__(256) void wn_all(
    const float* __restrict__ v_obj, const float* __restrict__ g_obj,
    const float* __restrict__ v_q,   const float* __restrict__ g_q,
    const float* __restrict__ v_l1,  const float* __restrict__ g_l1,
    const float* __restrict__ v_l2,  const float* __restrict__ g_l2,
    u16* __restrict__ Wobjh, u16* __restrict__ Wqh,
    u16* __restrict__ W1f,   u16* __restrict__ W2p) {
  const int b = blockIdx.x;
  const int sub = threadIdx.x >> 6, l = threadIdx.x & 63;
  if (b < 128) {
    wn_row(v_obj, g_obj, 2048, 512, Wobjh, b * 4 + sub, l);
  } else if (b < 256) {
    wn_row(v_q, g_q, 1024, 512, Wqh, (b - 128) * 4 + sub, l);
  } else if (b < 320) {
    const int row = (b - 256) * 4 + sub;
    const float* vr = v_l1 + (size_t)row * 512;
    float ss = 0.f;
    for (int k = l * 4; k < 512; k += 256) {
      f32x4 x = *(const f32x4*)(vr + k);
      ss += x.x * x.x + x.y * x.y + x.z * x.z + x.w * x.w;
    }
    #pragma unroll
    for (int m = 32; m >= 1; m >>= 1) ss += __shfl_xor(ss, m, 64);
    const float scale = g_l1[row] / sqrtf(ss);
    const int swz = (row >> 1) & 3;
    for (int c = l; c < 512; c += 64) {
      const int kc = c >> 5, col = c & 31, q = col >> 3, e = col & 7;
      W1f[kc * 8192 + row * 32 + ((q ^ swz) << 3) + e] = f2h(vr[c] * scale);
    }
  } else {
    wn_row(v_l2, g_l2, 256, 8, W2p, (b - 320) * 4 + sub, l);
  }
}

// ---- bulk fp32 -> fp16 convert ----
__global__ void cvt_f16(const float* __restrict__ in, u16* __restrict__ out, int n) {
  const int i = (blockIdx.x * 256 + threadIdx.x) * 8;
  if (i >= n) return;
  f32x4 a = *(const f32x4*)(in + i);
  f32x4 b = *(const f32x4*)(in + i + 4);
  uint4 r;
  r.x = pkrtz(a.x, a.y); r.y = pkrtz(a.z, a.w);
  r.z = pkrtz(b.x, b.y); r.w = pkrtz(b.z, b.w);
  *(uint4*)(out + i) = r;
}

// ---- pos map (stride 1408 per batch) ----
__global__ void pos_init(int* __restrict__ pos, int n) {
  int t = blockIdx.x * 256 + threadIdx.x;
  if (t < n) pos[t] = -1;
}
__global__ void pos_scatter(const int* __restrict__ indexes, int* __restrict__ pos, int n) {
  int m = blockIdx.x * 256 + threadIdx.x;
  if (m >= n) return;
  int idx = indexes[m];
  int bi = idx / 1296;
  int rem = idx - bi * 1296;
  pos[bi * 1408 + rem] = m;
}

// ================= LDS-staged stage-1 GEMM, fp16, 128x64 tile (unchanged) =================
template <int MODE>
__global__ __launch_bounds__(256, 3) void gemm_lds(
    const u16* __restrict__ Ab, const u16* __restrict__ Wb,
    int K, int nstep, const float* __restrict__ bias,
    float* __restrict__ fout, u16* __restrict__ o_a2) {
  __shared__ char smem[2][24576];
  const int t = threadIdx.x, l = t & 63, w = t >> 6;
  const int lr = l & 15, lg = l >> 4;
  const int wm = w & 1, wn2 = w >> 1;
  const int bm = blockIdx.x * 128, bn = blockIdx.y * 64;
  const int kbase = (MODE == 0) ? blockIdx.z * 128 : 0;
  const int ldb = K * 2;

  const char* Abase = (const char*)(Ab + (size_t)bm * K + kbase);
  const char* Bbase = (const char*)(Wb + (size_t)bn * K + kbase);

  auto stage = [&](int buf, int ks) {
    const char* asrc = Abase + ks * 128;
    const char* bsrc = Bbase + ks * 128;
    #pragma unroll
    for (int it = 0; it < 4; it++) {
      const int c = it * 256 + w * 64 + l;
      const int row = c >> 3;
      const int cb = ((c & 7) * 16) ^ ((row & 7) << 4);
      gload_lds16(asrc + (size_t)row * ldb + cb, &smem[buf][(it * 256 + w * 64) * 16]);
    }
    #pragma unroll
    for (int it = 0; it < 2; it++) {
      const int c = it * 256 + w * 64 + l;
      const int row = c >> 3;
      const int cb = ((c & 7) * 16) ^ ((row & 7) << 4);
      gload_lds16(bsrc + (size_t)row * ldb + cb,
                  &smem[buf][16384 + (it * 256 + w * 64) * 16]);
    }
  };

  stage(0, 0);
  asm volatile("s_waitcnt vmcnt(0)" ::: "memory");
  __builtin_amdgcn_s_barrier();

  f32x4 acc[4][2] = {};
  for (int ks = 0; ks < nstep; ks++) {
    const int cur = ks & 1;
    if (ks + 1 < nstep) stage(cur ^ 1, ks + 1);
    const char* As = smem[cur];
    const char* Bs = smem[cur] + 16384;
    #pragma unroll
    for (int kk = 0; kk < 2; kk++) {
      half8 af[4], bf[2];
      #pragma unroll
      for (int m = 0; m < 4; m++) {
        const int r = wm * 64 + m * 16 + lr;
        af[m] = ldh8(As + r * 128 + ((kk * 64 + lg * 16) ^ ((lr & 7) << 4)));
      }
      #pragma unroll
      for (int n = 0; n < 2; n++) {
        const int r = wn2 * 32 + n * 16 + lr;
        bf[n] = ldh8(Bs + r * 128 + ((kk * 64 + lg * 16) ^ ((lr & 7) << 4)));
      }
      #pragma unroll
      for (int m = 0; m < 4; m++)
        #pragma unroll
        for (int n = 0; n < 2; n++)
          acc[m][n] = mfma16h(af[m], bf[n], acc[m][n]);
    }
    asm volatile("s_waitcnt vmcnt(0)" ::: "memory");
    __builtin_amdgcn_s_barrier();
  }

  #pragma unroll
  for (int n = 0; n < 2; n++) {
    const int c = bn + wn2 * 32 + n * 16 + lr;
    const float bv = (MODE == 1) ? bias[c] : 0.f;
    #pragma unroll
    for (int m = 0; m < 4; m++) {
      #pragma unroll
      for (int q = 0; q < 4; q++) {
        const int r = bm + wm * 64 + m * 16 + lg * 4 + q;
        const float val = acc[m][n][q];
        if (MODE == 0) {
          fout[((size_t)blockIdx.z * 128 + r) * 512 + c] = val;
        } else {
          o_a2[(size_t)r * 512 + c] = f2h(val + bv);
        }
      }
    }
  }
}

// ---- split-K reduce for qp -> fp16 ----
__global__ void qp_reduce(const float* __restrict__ part, const float* __restrict__ bq,
                          u16* __restrict__ qp_h) {
  const int i = (blockIdx.x * 256 + threadIdx.x) * 4;
  f32x4 s = *(const f32x4*)(part + i);
  #pragma unroll
  for (int k = 1; k < 8; k++) {
    f32x4 v = *(const f32x4*)(part + (size_t)k * 65536 + i);
    s.x += v.x; s.y += v.y; s.z += v.z; s.w += v.w;
  }
  const int c = i & 511;
  uint2 r;
  r.x = pkrtz(s.x + bq[c], s.y + bq[c + 1]);
  r.y = pkrtz(s.z + bq[c + 2], s.w + bq[c + 3]);
  *(uint2*)(qp_h + i) = r;
}

// ================= fused edge kernel v10: 64x128 wave tile =================
// Block = batch bi x 128 E-rows, 4 waves (256 thr) as 2M x 2N; wave tile
// 64x128 (acc 4x8). LDS reads per wave-kc: 8 af-gen + 8 bf + 1 qv = 17 for
// 32 MFMA (v8: 13 for 16) -> per-CU LDS issue drops ~35%.
// v8 structure kept: qp folded at E-gen, W1 pre-swizzled async double-buffer,
// one barrier per kc. LDS: nf 36x1040 | qp 1KB | W1 dbuf 2x16384 = 71,232 B
// -> 2 blocks/CU (8 waves).
#define OFF_QP 37440
#define OFF_W1 38464
#define EDGE_SMEM 71232

__global__ __launch_bounds__(256, 2) void edge_v10(
    const u16* __restrict__ NFg, const u16* __restrict__ QPg,
    const u16* __restrict__ W1f, const float* __restrict__ b1,
    const u16* __restrict__ W2p, const float* __restrict__ b2,
    const int* __restrict__ pos, float* __restrict__ out) {
  extern __shared__ char smem[];
  const int t = threadIdx.x, l = t & 63, w = t >> 6;
  const int lr = l & 15, lg = l >> 4;
  const int wm = w & 1, wn = w >> 1;
  const int bi = blockIdx.y;
  const int mb = blockIdx.x * 128;

  // ---- prologue: nf rows 0..35 + qp row + W1 chunk 0 ----
  #pragma unroll
  for (int it = 0; it < 10; it++) {
    const int row = it * 4 + w;            // wave-uniform
    if (row < 36) {
      gload_lds16(NFg + (size_t)(bi * 36 + row) * 512 + l * 8, smem + row * 1040);
    } else if (row == 36) {
      gload_lds16(QPg + (size_t)bi * 512 + l * 8, smem + OFF_QP);
    }
  }
  #pragma unroll
  for (int it = 0; it < 4; it++) {
    gload_lds16(W1f + (size_t)(it * 256 + w * 64 + l) * 8,
                smem + OFF_W1 + (it * 256 + w * 64) * 16);
  }

  // ---- per-thread A-gen offsets for the 4 m-tiles ----
  int xoff[4], yoff[4];
  #pragma unroll
  for (int m = 0; m < 4; m++) {
    const int gr = mb + wm * 64 + m * 16 + lr;
    const int iiu = gr / 36;
    const int jj = gr - iiu * 36;
    const int ii = (iiu > 35) ? 35 : iiu;
    xoff[m] = ii * 1040 + lg * 16;
    yoff[m] = jj * 1040 + lg * 16;
  }
  const int qoff = OFF_QP + lg * 16;
  const int bswz = ((lr >> 1) & 3) << 4;

  asm volatile("s_waitcnt vmcnt(0)" ::: "memory");
  __builtin_amdgcn_s_barrier();

  f32x4 acc[4][8] = {};
  int cur = 0;

  for (int kc = 0; kc < 16; kc++) {
    const int nxt = cur ^ 1;
    if (kc < 15) {                         // async W1(kc+1) -> buf nxt
      #pragma unroll
      for (int it = 0; it < 4; it++) {
        gload_lds16(W1f + (size_t)(kc + 1) * 8192 + (size_t)(it * 256 + w * 64 + l) * 8,
                    smem + OFF_W1 + nxt * 16384 + (it * 256 + w * 64) * 16);
      }
    }
    // MFMA(kc): bf[8] from W1[cur] (XOR-swizzled), af = x*y*q in regs
    {
      const char* w1c = smem + OFF_W1 + cur * 16384;
      const int kb = kc * 64;
      const uint4 qv = *(const uint4*)(smem + qoff + kb);
      half8 bf[8];
      #pragma unroll
      for (int n = 0; n < 8; n++)
        bf[n] = ldh8(w1c + (wn * 128 + n * 16 + lr) * 64 + ((lg * 16) ^ bswz));
      #pragma unroll
      for (int m = 0; m < 4; m++) {
        uint4 x = *(const uint4*)(smem + xoff[m] + kb);
        uint4 y = *(const uint4*)(smem + yoff[m] + kb);
        half8 af = as_h8(pkmul4(pkmul4(x, y), qv));
        #pragma unroll
        for (int n = 0; n < 8; n++)
          acc[m][n] = mfma16h(af, bf[n], acc[m][n]);
      }
    }
    asm volatile("s_waitcnt vmcnt(0)" ::: "memory");   // own W1 DMA landed (covered by MFMA)
    __builtin_amdgcn_s_barrier();
    cur = nxt;
  }

  // ---- epilogue: bias+relu -> fp16 h tile [128][528B] (aliases nf/W1) ----
  #pragma unroll
  for (int m = 0; m < 4; m++) {
    #pragma unroll
    for (int n = 0; n < 8; n++) {
      const int c = wn * 128 + n * 16 + lr;
      const float bv = b1[c];
      #pragma unroll
      for (int qq = 0; qq < 2; qq++) {
        const float v0 = fmaxf(acc[m][n][2 * qq] + bv, 0.f);
        const float v1 = fmaxf(acc[m][n][2 * qq + 1] + bv, 0.f);
        const u32 p = pkrtz(v0, v1);
        const int r = wm * 64 + m * 16 + lg * 4 + 2 * qq;
        *(u16*)(smem + r * 528 + c * 2) = (u16)p;
        *(u16*)(smem + (r + 1) * 528 + c * 2) = (u16)(p >> 16);
      }
    }
  }
  __syncthreads();

  // ---- GEMM2: out = h @ W2p^T + b2, K=256 fp16; 8 row-tiles over 4 waves ----
  half8 w2f[8];
  #pragma unroll
  for (int kk = 0; kk < 8; kk++)
    w2f[kk] = ldh8((const char*)(W2p + lr * 256 + kk * 32 + lg * 8));

  #pragma unroll
  for (int tt = 0; tt < 2; tt++) {
    const int tile = tt * 4 + w;
    f32x4 a2c = {0.f, 0.f, 0.f, 0.f};
    #pragma unroll
    for (int kk = 0; kk < 8; kk++) {
      half8 af = ldh8(smem + (tile * 16 + lr) * 528 + kk * 64 + lg * 16);
      a2c = mfma16h(af, w2f[kk], a2c);
    }
    if (lr < 8) {
      const float b2v = b2[lr];
      #pragma unroll
      for (int q = 0; q < 4; q++) {
        const int rl = tile * 16 + lg * 4 + q;
        const int m = pos[bi * 1408 + mb + rl];
        if (m >= 0) out[(size_t)m * 8 + lr] = a2c[q] + b2v;
      }
    }
  }
}

extern "C" void kernel_launch(void* const* d_in, const int* in_sizes, int n_in,
                              void* d_out, int out_size, void* d_ws, size_t ws_size,
                              hipStream_t stream) {
  const float* node_feats = (const float*)d_in[0];
  const float* q_feats    = (const float*)d_in[1];
  const int*   indexes    = (const int*)d_in[2];
  const float* v_obj = (const float*)d_in[3];
  const float* g_obj = (const float*)d_in[4];
  const float* b_obj = (const float*)d_in[5];
  const float* v_q   = (const float*)d_in[6];
  const float* g_q   = (const float*)d_in[7];
  const float* b_q   = (const float*)d_in[8];
  const float* v_l1  = (const float*)d_in[9];
  const float* g_l1  = (const float*)d_in[10];
  const float* b_l1  = (const float*)d_in[11];
  const float* v_l2  = (const float*)d_in[12];
  const float* g_l2  = (const float*)d_in[13];
  const float* b_l2  = (const float*)d_in[14];
  float* out = (float*)d_out;

  char* ws = (char*)d_ws;
  u16*   node_h = (u16*)(ws + 0);               // 18,874,368
  u16*   q_h    = (u16*)(ws + 18874368);        //    262,144
  u16*   Wobjh  = (u16*)(ws + 19136512);        //  2,097,152
  u16*   Wqh    = (u16*)(ws + 21233664);        //  1,048,576
  u16*   W1f    = (u16*)(ws + 22282240);        //    262,144 (16x256x32 fp16, swz)
  u16*   W2p    = (u16*)(ws + 22544384);        //      8,192
  u16*   qp_h   = (u16*)(ws + 22552576);        //    131,072 (128x512 fp16)
  u16*   A2h    = (u16*)(ws + 22683648);        //  4,718,592 (nf fp16)
  int*   pos    = (int*)(ws + 27402240);        //    720,896 (128x1408)
  float* part   = (float*)(ws + 28123136);      //  2,097,152

  wn_all<<<dim3(324), dim3(256), 0, stream>>>(v_obj, g_obj, v_q, g_q, v_l1, g_l1,
                                              v_l2, g_l2, Wobjh, Wqh, W1f, W2p);

  cvt_f16<<<dim3(4608), dim3(256), 0, stream>>>(node_feats, node_h, 9437184);
  cvt_f16<<<dim3(64),   dim3(256), 0, stream>>>(q_feats,    q_h,    131072);

  pos_init<<<dim3(704), dim3(256), 0, stream>>>(pos, 128 * 1408);
  pos_scatter<<<dim3(630), dim3(256), 0, stream>>>(indexes, pos, 161280);

  gemm_lds<0><<<dim3(1, 8, 8), dim3(256), 0, stream>>>(q_h, Wqh, 1024, 2, nullptr,
                                                       part, nullptr);
  qp_reduce<<<dim3(64), dim3(256), 0, stream>>>(part, b_q, qp_h);

  gemm_lds<1><<<dim3(36, 8), dim3(256), 0, stream>>>(node_h, Wobjh, 2048, 32, b_obj,
                                                     nullptr, A2h);

  edge_v10<<<dim3(11, 128), dim3(256), EDGE_SMEM, stream>>>(A2h, qp_h, W1f, b_l1,
                                                            W2p, b_l2, pos, out);
}

// Round 12
// 99.239 us; speedup vs baseline: 1.4143x; 1.2078x over previous
//
#include <hip/hip_runtime.h>
#include <hip/hip_fp16.h>

typedef __attribute__((ext_vector_type(8))) _Float16 half8;
typedef __attribute__((ext_vector_type(2))) __fp16 fp16x2;
typedef __attribute__((ext_vector_type(4))) float f32x4;
typedef unsigned short u16;
typedef unsigned int u32;

__device__ __forceinline__ u16 f2h(float f) {
  union { _Float16 h; u16 u; } cv; cv.h = (_Float16)f; return cv.u;
}

__device__ __forceinline__ u32 pkrtz(float a, float b) {
  union { fp16x2 h; u32 u; } cv;
  cv.h = __builtin_amdgcn_cvt_pkrtz(a, b);
  return cv.u;
}

__device__ __forceinline__ f32x4 mfma16h(half8 a, half8 b, f32x4 c) {
  return __builtin_amdgcn_mfma_f32_16x16x32_f16(a, b, c, 0, 0, 0);
}

__device__ __forceinline__ void gload_lds16(const void* g, void* l) {
  __builtin_amdgcn_global_load_lds(
      (const __attribute__((address_space(1))) void*)g,
      (__attribute__((address_space(3))) void*)l, 16, 0, 0);
}

__device__ __forceinline__ half8 ldh8(const char* p) {
  union { half8 h; int4 v; } r; r.v = *(const int4*)p; return r.h;
}

// 8-wide fp16 product via v_pk_mul_f16
__device__ __forceinline__ uint4 pkmul4(uint4 x, uint4 y) {
  union U { uint4 v; __half2 h[4]; };
  U X, Y, E; X.v = x; Y.v = y;
  #pragma unroll
  for (int i = 0; i < 4; i++) E.h[i] = __hmul2(X.h[i], Y.h[i]);
  return E.v;
}
__device__ __forceinline__ half8 as_h8(uint4 v) {
  union { uint4 v; half8 h; } r; r.v = v; return r.h;
}

// ---- one row of weight-norm (fp16 out), wave-cooperative ----
__device__ __forceinline__ void wn_row(const float* __restrict__ v,
                                       const float* __restrict__ g,
                                       int K, int Nreal, u16* __restrict__ outW,
                                       int row, int l) {
  if (row >= Nreal) {
    for (int k = l; k < K; k += 64) outW[row * K + k] = 0;
    return;
  }
  const float* vr = v + (size_t)row * K;
  float ss = 0.f;
  for (int k = l * 4; k < K; k += 256) {
    f32x4 x = *(const f32x4*)(vr + k);
    ss += x.x * x.x + x.y * x.y + x.z * x.z + x.w * x.w;
  }
  #pragma unroll
  for (int m = 32; m >= 1; m >>= 1) ss += __shfl_xor(ss, m, 64);
  const float scale = g[row] / sqrtf(ss);
  for (int k = l; k < K; k += 64) outW[row * K + k] = f2h(vr[k] * scale);
}

// ---- merged weight-norm prep ----
__global__ __launch_bounds__(256) void wn_all(
    const float* __restrict__ v_obj, const float* __restrict__ g_obj,
    const float* __restrict__ v_q,   const float* __restrict__ g_q,
    const float* __restrict__ v_l1,  const float* __restrict__ g_l1,
    const float* __restrict__ v_l2,  const float* __restrict__ g_l2,
    u16* __restrict__ Wobjh, u16* __restrict__ Wqh,
    u16* __restrict__ W1f,   u16* __restrict__ W2p) {
  const int b = blockIdx.x;
  const int sub = threadIdx.x >> 6, l = threadIdx.x & 63;
  if (b < 128) {
    wn_row(v_obj, g_obj, 2048, 512, Wobjh, b * 4 + sub, l);
  } else if (b < 256) {
    wn_row(v_q, g_q, 1024, 512, Wqh, (b - 128) * 4 + sub, l);
  } else if (b < 320) {
    const int row = (b - 256) * 4 + sub;
    const float* vr = v_l1 + (size_t)row * 512;
    float ss = 0.f;
    for (int k = l * 4; k < 512; k += 256) {
      f32x4 x = *(const f32x4*)(vr + k);
      ss += x.x * x.x + x.y * x.y + x.z * x.z + x.w * x.w;
    }
    #pragma unroll
    for (int m = 32; m >= 1; m >>= 1) ss += __shfl_xor(ss, m, 64);
    const float scale = g_l1[row] / sqrtf(ss);
    const int swz = (row >> 1) & 3;
    for (int c = l; c < 512; c += 64) {
      const int kc = c >> 5, col = c & 31, q = col >> 3, e = col & 7;
      W1f[kc * 8192 + row * 32 + ((q ^ swz) << 3) + e] = f2h(vr[c] * scale);
    }
  } else {
    wn_row(v_l2, g_l2, 256, 8, W2p, (b - 320) * 4 + sub, l);
  }
}

// ---- bulk fp32 -> fp16 convert ----
__global__ void cvt_f16(const float* __restrict__ in, u16* __restrict__ out, int n) {
  const int i = (blockIdx.x * 256 + threadIdx.x) * 8;
  if (i >= n) return;
  f32x4 a = *(const f32x4*)(in + i);
  f32x4 b = *(const f32x4*)(in + i + 4);
  uint4 r;
  r.x = pkrtz(a.x, a.y); r.y = pkrtz(a.z, a.w);
  r.z = pkrtz(b.x, b.y); r.w = pkrtz(b.z, b.w);
  *(uint4*)(out + i) = r;
}

// ---- symmetric-pair maps ----
// posPair[bi][p][2]: output rows for unordered pair p (slot 0: i<j, slot 1: i>j).
// ij_tab[p] = i*36+j (i<j); pads [630,640) -> 35*36+35.
__global__ void pos_init(int* __restrict__ posPair, int* __restrict__ ij_tab, int n) {
  const int t = blockIdx.x * 256 + threadIdx.x;
  if (t < n) posPair[t] = -1;
  if (t < 1296) {
    const int i = t / 36, j = t - i * 36;
    if (i < j) ij_tab[i * (71 - i) / 2 + (j - i - 1)] = t;
  } else if (t < 1306) {
    ij_tab[630 + (t - 1296)] = 35 * 36 + 35;
  }
}
__global__ void pos_scatter(const int* __restrict__ indexes, int* __restrict__ posPair, int n) {
  const int m = blockIdx.x * 256 + threadIdx.x;
  if (m >= n) return;
  const int idx = indexes[m];
  const int bi = idx / 1296;
  const int rem = idx - bi * 1296;
  const int i = rem / 36, j = rem - i * 36;
  const int i2 = (i < j) ? i : j, j2 = (i < j) ? j : i;
  const int p = i2 * (71 - i2) / 2 + (j2 - i2 - 1);
  posPair[(bi * 640 + p) * 2 + ((i < j) ? 0 : 1)] = m;
}

// ================= LDS-staged stage-1 GEMM, fp16, 128x64 tile (unchanged) =================
template <int MODE>
__global__ __launch_bounds__(256, 3) void gemm_lds(
    const u16* __restrict__ Ab, const u16* __restrict__ Wb,
    int K, int nstep, const float* __restrict__ bias,
    float* __restrict__ fout, u16* __restrict__ o_a2) {
  __shared__ char smem[2][24576];
  const int t = threadIdx.x, l = t & 63, w = t >> 6;
  const int lr = l & 15, lg = l >> 4;
  const int wm = w & 1, wn2 = w >> 1;
  const int bm = blockIdx.x * 128, bn = blockIdx.y * 64;
  const int kbase = (MODE == 0) ? blockIdx.z * 128 : 0;
  const int ldb = K * 2;

  const char* Abase = (const char*)(Ab + (size_t)bm * K + kbase);
  const char* Bbase = (const char*)(Wb + (size_t)bn * K + kbase);

  auto stage = [&](int buf, int ks) {
    const char* asrc = Abase + ks * 128;
    const char* bsrc = Bbase + ks * 128;
    #pragma unroll
    for (int it = 0; it < 4; it++) {
      const int c = it * 256 + w * 64 + l;
      const int row = c >> 3;
      const int cb = ((c & 7) * 16) ^ ((row & 7) << 4);
      gload_lds16(asrc + (size_t)row * ldb + cb, &smem[buf][(it * 256 + w * 64) * 16]);
    }
    #pragma unroll
    for (int it = 0; it < 2; it++) {
      const int c = it * 256 + w * 64 + l;
      const int row = c >> 3;
      const int cb = ((c & 7) * 16) ^ ((row & 7) << 4);
      gload_lds16(bsrc + (size_t)row * ldb + cb,
                  &smem[buf][16384 + (it * 256 + w * 64) * 16]);
    }
  };

  stage(0, 0);
  asm volatile("s_waitcnt vmcnt(0)" ::: "memory");
  __builtin_amdgcn_s_barrier();

  f32x4 acc[4][2] = {};
  for (int ks = 0; ks < nstep; ks++) {
    const int cur = ks & 1;
    if (ks + 1 < nstep) stage(cur ^ 1, ks + 1);
    const char* As = smem[cur];
    const char* Bs = smem[cur] + 16384;
    #pragma unroll
    for (int kk = 0; kk < 2; kk++) {
      half8 af[4], bf[2];
      #pragma unroll
      for (int m = 0; m < 4; m++) {
        const int r = wm * 64 + m * 16 + lr;
        af[m] = ldh8(As + r * 128 + ((kk * 64 + lg * 16) ^ ((lr & 7) << 4)));
      }
      #pragma unroll
      for (int n = 0; n < 2; n++) {
        const int r = wn2 * 32 + n * 16 + lr;
        bf[n] = ldh8(Bs + r * 128 + ((kk * 64 + lg * 16) ^ ((lr & 7) << 4)));
      }
      #pragma unroll
      for (int m = 0; m < 4; m++)
        #pragma unroll
        for (int n = 0; n < 2; n++)
          acc[m][n] = mfma16h(af[m], bf[n], acc[m][n]);
    }
    asm volatile("s_waitcnt vmcnt(0)" ::: "memory");
    __builtin_amdgcn_s_barrier();
  }

  #pragma unroll
  for (int n = 0; n < 2; n++) {
    const int c = bn + wn2 * 32 + n * 16 + lr;
    const float bv = (MODE == 1) ? bias[c] : 0.f;
    #pragma unroll
    for (int m = 0; m < 4; m++) {
      #pragma unroll
      for (int q = 0; q < 4; q++) {
        const int r = bm + wm * 64 + m * 16 + lg * 4 + q;
        const float val = acc[m][n][q];
        if (MODE == 0) {
          fout[((size_t)blockIdx.z * 128 + r) * 512 + c] = val;
        } else {
          o_a2[(size_t)r * 512 + c] = f2h(val + bv);
        }
      }
    }
  }
}

// ---- split-K reduce for qp -> fp16 ----
__global__ void qp_reduce(const float* __restrict__ part, const float* __restrict__ bq,
                          u16* __restrict__ qp_h) {
  const int i = (blockIdx.x * 256 + threadIdx.x) * 4;
  f32x4 s = *(const f32x4*)(part + i);
  #pragma unroll
  for (int k = 1; k < 8; k++) {
    f32x4 v = *(const f32x4*)(part + (size_t)k * 65536 + i);
    s.x += v.x; s.y += v.y; s.z += v.z; s.w += v.w;
  }
  const int c = i & 511;
  uint2 r;
  r.x = pkrtz(s.x + bq[c], s.y + bq[c + 1]);
  r.y = pkrtz(s.z + bq[c + 2], s.w + bq[c + 3]);
  *(uint2*)(qp_h + i) = r;
}

// ================= fused edge kernel v11: symmetric pairs (i<j only) =================
// out[(i,j)] == out[(j,i)] (elementwise mul is symmetric; q is per-batch) ->
// compute the 630 unordered pairs per batch (pad 640), scatter to both rows.
// Structure = v10 (64x128 wave tile, qp broadcast, W1 pre-swizzled async dbuf,
// one barrier/kc). Row p -> (i,j) via ij_tab. Grid (5, 128) = 640 blocks.
#define OFF_QP 37440
#define OFF_W1 38464
#define EDGE_SMEM 71232

__global__ __launch_bounds__(256, 2) void edge_v11(
    const u16* __restrict__ NFg, const u16* __restrict__ QPg,
    const u16* __restrict__ W1f, const float* __restrict__ b1,
    const u16* __restrict__ W2p, const float* __restrict__ b2,
    const int* __restrict__ posPair, const int* __restrict__ ij_tab,
    float* __restrict__ out) {
  extern __shared__ char smem[];
  const int t = threadIdx.x, l = t & 63, w = t >> 6;
  const int lr = l & 15, lg = l >> 4;
  const int wm = w & 1, wn = w >> 1;
  const int bi = blockIdx.y;
  const int mb = blockIdx.x * 128;

  // ---- prologue: nf rows 0..35 + qp row + W1 chunk 0 ----
  #pragma unroll
  for (int it = 0; it < 10; it++) {
    const int row = it * 4 + w;            // wave-uniform
    if (row < 36) {
      gload_lds16(NFg + (size_t)(bi * 36 + row) * 512 + l * 8, smem + row * 1040);
    } else if (row == 36) {
      gload_lds16(QPg + (size_t)bi * 512 + l * 8, smem + OFF_QP);
    }
  }
  #pragma unroll
  for (int it = 0; it < 4; it++) {
    gload_lds16(W1f + (size_t)(it * 256 + w * 64 + l) * 8,
                smem + OFF_W1 + (it * 256 + w * 64) * 16);
  }

  // ---- per-thread A-gen offsets for the 4 m-tiles (pair -> i,j via ij_tab) ----
  int xoff[4], yoff[4];
  #pragma unroll
  for (int m = 0; m < 4; m++) {
    const int p = mb + wm * 64 + m * 16 + lr;       // pair row (pad safe: tab=35,35)
    const int pij = ij_tab[p];
    const int ii = pij / 36;
    const int jj = pij - ii * 36;
    xoff[m] = ii * 1040 + lg * 16;
    yoff[m] = jj * 1040 + lg * 16;
  }
  const int qoff = OFF_QP + lg * 16;
  const int bswz = ((lr >> 1) & 3) << 4;

  asm volatile("s_waitcnt vmcnt(0)" ::: "memory");
  __builtin_amdgcn_s_barrier();

  f32x4 acc[4][8] = {};
  int cur = 0;

  for (int kc = 0; kc < 16; kc++) {
    const int nxt = cur ^ 1;
    if (kc < 15) {                         // async W1(kc+1) -> buf nxt
      #pragma unroll
      for (int it = 0; it < 4; it++) {
        gload_lds16(W1f + (size_t)(kc + 1) * 8192 + (size_t)(it * 256 + w * 64 + l) * 8,
                    smem + OFF_W1 + nxt * 16384 + (it * 256 + w * 64) * 16);
      }
    }
    // MFMA(kc): bf[8] from W1[cur] (XOR-swizzled), af = x*y*q in regs
    {
      const char* w1c = smem + OFF_W1 + cur * 16384;
      const int kb = kc * 64;
      const uint4 qv = *(const uint4*)(smem + qoff + kb);
      half8 bf[8];
      #pragma unroll
      for (int n = 0; n < 8; n++)
        bf[n] = ldh8(w1c + (wn * 128 + n * 16 + lr) * 64 + ((lg * 16) ^ bswz));
      #pragma unroll
      for (int m = 0; m < 4; m++) {
        uint4 x = *(const uint4*)(smem + xoff[m] + kb);
        uint4 y = *(const uint4*)(smem + yoff[m] + kb);
        half8 af = as_h8(pkmul4(pkmul4(x, y), qv));
        #pragma unroll
        for (int n = 0; n < 8; n++)
          acc[m][n] = mfma16h(af, bf[n], acc[m][n]);
      }
    }
    asm volatile("s_waitcnt vmcnt(0)" ::: "memory");   // own W1 DMA landed (covered by MFMA)
    __builtin_amdgcn_s_barrier();
    cur = nxt;
  }

  // ---- epilogue: bias+relu -> fp16 h tile [128][528B] (aliases nf/W1) ----
  #pragma unroll
  for (int m = 0; m < 4; m++) {
    #pragma unroll
    for (int n = 0; n < 8; n++) {
      const int c = wn * 128 + n * 16 + lr;
      const float bv = b1[c];
      #pragma unroll
      for (int qq = 0; qq < 2; qq++) {
        const float v0 = fmaxf(acc[m][n][2 * qq] + bv, 0.f);
        const float v1 = fmaxf(acc[m][n][2 * qq + 1] + bv, 0.f);
        const u32 pk = pkrtz(v0, v1);
        const int r = wm * 64 + m * 16 + lg * 4 + 2 * qq;
        *(u16*)(smem + r * 528 + c * 2) = (u16)pk;
        *(u16*)(smem + (r + 1) * 528 + c * 2) = (u16)(pk >> 16);
      }
    }
  }
  __syncthreads();

  // ---- GEMM2: out = h @ W2p^T + b2, K=256; dual scatter to both orderings ----
  half8 w2f[8];
  #pragma unroll
  for (int kk = 0; kk < 8; kk++)
    w2f[kk] = ldh8((const char*)(W2p + lr * 256 + kk * 32 + lg * 8));

  #pragma unroll
  for (int tt = 0; tt < 2; tt++) {
    const int tile = tt * 4 + w;
    f32x4 a2c = {0.f, 0.f, 0.f, 0.f};
    #pragma unroll
    for (int kk = 0; kk < 8; kk++) {
      half8 af = ldh8(smem + (tile * 16 + lr) * 528 + kk * 64 + lg * 16);
      a2c = mfma16h(af, w2f[kk], a2c);
    }
    if (lr < 8) {
      const float b2v = b2[lr];
      #pragma unroll
      for (int q = 0; q < 4; q++) {
        const int p = mb + tile * 16 + lg * 4 + q;
        const int m0 = posPair[(bi * 640 + p) * 2];
        const int m1 = posPair[(bi * 640 + p) * 2 + 1];
        const float val = a2c[q] + b2v;
        if (m0 >= 0) out[(size_t)m0 * 8 + lr] = val;
        if (m1 >= 0) out[(size_t)m1 * 8 + lr] = val;
      }
    }
  }
}

extern "C" void kernel_launch(void* const* d_in, const int* in_sizes, int n_in,
                              void* d_out, int out_size, void* d_ws, size_t ws_size,
                              hipStream_t stream) {
  const float* node_feats = (const float*)d_in[0];
  const float* q_feats    = (const float*)d_in[1];
  const int*   indexes    = (const int*)d_in[2];
  const float* v_obj = (const float*)d_in[3];
  const float* g_obj = (const float*)d_in[4];
  const float* b_obj = (const float*)d_in[5];
  const float* v_q   = (const float*)d_in[6];
  const float* g_q   = (const float*)d_in[7];
  const float* b_q   = (const float*)d_in[8];
  const float* v_l1  = (const float*)d_in[9];
  const float* g_l1  = (const float*)d_in[10];
  const float* b_l1  = (const float*)d_in[11];
  const float* v_l2  = (const float*)d_in[12];
  const float* g_l2  = (const float*)d_in[13];
  const float* b_l2  = (const float*)d_in[14];
  float* out = (float*)d_out;

  char* ws = (char*)d_ws;
  u16*   node_h  = (u16*)(ws + 0);               // 18,874,368
  u16*   q_h     = (u16*)(ws + 18874368);        //    262,144
  u16*   Wobjh   = (u16*)(ws + 19136512);        //  2,097,152
  u16*   Wqh     = (u16*)(ws + 21233664);        //  1,048,576
  u16*   W1f     = (u16*)(ws + 22282240);        //    262,144 (16x256x32 fp16, swz)
  u16*   W2p     = (u16*)(ws + 22544384);        //      8,192
  u16*   qp_h    = (u16*)(ws + 22552576);        //    131,072 (128x512 fp16)
  u16*   A2h     = (u16*)(ws + 22683648);        //  4,718,592 (nf fp16)
  int*   posPair = (int*)(ws + 27402240);        //    655,360 (128x640x2)
  int*   ij_tab  = (int*)(ws + 28057600);        //      2,560 (640)
  float* part    = (float*)(ws + 28060160);      //  2,097,152

  wn_all<<<dim3(324), dim3(256), 0, stream>>>(v_obj, g_obj, v_q, g_q, v_l1, g_l1,
                                              v_l2, g_l2, Wobjh, Wqh, W1f, W2p);

  cvt_f16<<<dim3(4608), dim3(256), 0, stream>>>(node_feats, node_h, 9437184);
  cvt_f16<<<dim3(64),   dim3(256), 0, stream>>>(q_feats,    q_h,    131072);

  pos_init<<<dim3(640), dim3(256), 0, stream>>>(posPair, ij_tab, 128 * 640 * 2);
  pos_scatter<<<dim3(630), dim3(256), 0, stream>>>(indexes, posPair, 161280);

  gemm_lds<0><<<dim3(1, 8, 8), dim3(256), 0, stream>>>(q_h, Wqh, 1024, 2, nullptr,
                                                       part, nullptr);
  qp_reduce<<<dim3(64), dim3(256), 0, stream>>>(part, b_q, qp_h);

  gemm_lds<1><<<dim3(36, 8), dim3(256), 0, stream>>>(node_h, Wobjh, 2048, 32, b_obj,
                                                     nullptr, A2h);

  edge_v11<<<dim3(5, 128), dim3(256), EDGE_SMEM, stream>>>(A2h, qp_h, W1f, b_l1,
                                                           W2p, b_l2, posPair, ij_tab, out);
}